// Round 6
// baseline (75434.259 us; speedup 1.0000x reference)
//
#include <hip/hip_runtime.h>
#include <math.h>

// Persistent-kernel DDE solver. D=256, H=1024, N_TAU=10; N from out_size.
// 32 WGs x 256 threads; weights register-resident; per-WG LDS ring for the
// delayed state.
//
// R4 change (fused barrier): the counter barrier cost 2 extra coherence-point
// round trips per step (leader fetch_add + leader poll) plus 2 __syncthreads.
// Replaced by epoch-tagged data polling: each thread publishes {tag=s+1,
// partial} as one 8B relaxed agent-scope atomic store; the gather polls the
// 32 tagged slots directly until all carry tag s+1, then sums in fixed ww
// order (bitwise-deterministic across replays). Parity double-buffer makes
// slot reuse at s+2 race-free: WG w can only reach its s+2 publish after
// gathering every WG's s+1 partial, whose values data-depend on that WG
// having read w's s partial. 0xAA ws-poison never matches a tag (tags are
// 1..N), so no memset and no counter at all. 2 __syncthreads/step remain
// (hsh ready; state update visible).

#define NTAU 10
#define DD   256
#define HH   1024
#define NWG  32
#define TPB  256
#define HPW  (HH / NWG)   // 32 h-rows per WG
#define KPT  64           // z elements per thread (layer 1)

typedef unsigned long long u64;
typedef unsigned int       u32;

__global__ __launch_bounds__(TPB, 1)
void ndde_persist(const float* __restrict__ x0,
                  const float* __restrict__ W1,
                  const float* __restrict__ b1,
                  const float* __restrict__ W2,
                  const float* __restrict__ b2,
                  const int*   __restrict__ taup,
                  float* __restrict__ out,   // [DD][N+1] row-major
                  u64*          P,           // [2][NWG][DD] tagged partials (d_ws)
                  int N)
{
    const int w  = blockIdx.x;     // 0..31
    const int t  = threadIdx.x;    // 0..255
    const int r  = t >> 3;         // row-in-WG 0..31
    const int i  = t & 7;          // k-chunk 0..7 (i<4 -> x part, i>=4 -> y part)
    const int row  = w * HPW + r;  // global h row this (r-group) computes
    const int col0 = w * HPW;      // W2 column base for layer 2

    const float dt = 0.1f * (float)(*taup);

    __shared__ __align__(16) float xcur[DD];
    __shared__ __align__(16) float hist[NTAU][DD];  // ring: slot s%10 holds x_{s-10}
    __shared__ __align__(16) float hsh[HPW];

    // ---- prologue: weights -> registers ----
    // Layer-1 chunk: W1[row][i*64 + 4*((j+i)&15) + c]  (j-rotation by i spreads
    // the 8 per-wave LDS broadcast addresses across 8 distinct bank-quads).
    float4 w1r[16];
    {
        const float* wrow = W1 + (size_t)row * (2 * DD);
        #pragma unroll
        for (int j = 0; j < 16; ++j) {
            int jj = (j + i) & 15;
            w1r[j] = *(const float4*)(wrow + i * KPT + 4 * jj);
        }
    }
    // Layer-2 chunk: W2[t][col0 .. col0+32)
    float4 w2r[8];
    #pragma unroll
    for (int c = 0; c < 8; ++c)
        w2r[c] = *(const float4*)(W2 + (size_t)t * HH + col0 + 4 * c);

    const float b1r = b1[row];
    const float b2r = b2[t];
    const float x0r = x0[t];
    const bool  writer = (r == w);            // WG w owns output rows [8w, 8w+8)
    float* orow = out + (size_t)t * (N + 1);  // this thread's output row

    xcur[t] = x0r;
    #pragma unroll
    for (int q = 0; q < NTAU; ++q) hist[q][t] = x0r;
    if (writer) orow[0] = x0r;
    __syncthreads();

    int hidx = 0;  // s % NTAU
    for (int s = 0; s < N; ++s) {
        // ---- layer 1: acc = sum_k W1[row][chunk] * z[chunk] ----
        const float* zbase = (i < 4) ? (xcur + (i & 3) * KPT)
                                     : (hist[hidx] + (i & 3) * KPT);
        float ax = 0.f, ay = 0.f, az = 0.f, aw = 0.f;  // 4 indep FMA chains
        #pragma unroll
        for (int j = 0; j < 16; ++j) {
            int jj = (j + i) & 15;
            float4 zv = *(const float4*)(zbase + 4 * jj);
            float4 wv = w1r[j];
            ax = fmaf(wv.x, zv.x, ax);
            ay = fmaf(wv.y, zv.y, ay);
            az = fmaf(wv.z, zv.z, az);
            aw = fmaf(wv.w, zv.w, aw);
        }
        float acc = (ax + ay) + (az + aw);
        // reduce the 8 k-chunk lanes (contiguous within wave)
        acc += __shfl_xor(acc, 1);
        acc += __shfl_xor(acc, 2);
        acc += __shfl_xor(acc, 4);
        if (i == 0) hsh[r] = tanhf(acc + b1r);
        __syncthreads();                       // hsh ready for layer 2

        // ---- layer 2: partial_d = sum_c W2[d][col0+c] * h[col0+c] ----
        float px = 0.f, py = 0.f, pz = 0.f, pw = 0.f;
        #pragma unroll
        for (int c = 0; c < 8; ++c) {
            float4 hv = *(const float4*)(&hsh[4 * c]);  // same-addr broadcast
            float4 wv = w2r[c];
            px = fmaf(wv.x, hv.x, px);
            py = fmaf(wv.y, hv.y, py);
            pz = fmaf(wv.z, hv.z, pz);
            pw = fmaf(wv.w, hv.w, pw);
        }
        float p = (px + py) + (pz + pw);

        // ---- publish tagged partial: one 8B relaxed agent atomic store ----
        const u32 tag = (u32)(s + 1);
        u64* slot = P + ((size_t)(s & 1) * NWG + w) * DD + t;
        const u64 pk = ((u64)tag << 32) | (u64)__float_as_uint(p);
        __hip_atomic_store(slot, pk, __ATOMIC_RELAXED, __HIP_MEMORY_SCOPE_AGENT);

        // ---- gather: pipelined sweep, per-slot fixup poll, ordered sum ----
        u64* gbase = P + (size_t)(s & 1) * NWG * DD + t;
        u64 v[NWG];
        #pragma unroll
        for (int ww = 0; ww < NWG; ++ww)
            v[ww] = __hip_atomic_load(gbase + (size_t)ww * DD,
                                      __ATOMIC_RELAXED, __HIP_MEMORY_SCOPE_AGENT);
        #pragma unroll
        for (int ww = 0; ww < NWG; ++ww) {
            while (!__all((int)((u32)(v[ww] >> 32) == tag)))
                v[ww] = __hip_atomic_load(gbase + (size_t)ww * DD,
                                          __ATOMIC_RELAXED, __HIP_MEMORY_SCOPE_AGENT);
        }
        float delta = 0.f;
        #pragma unroll
        for (int ww = 0; ww < NWG; ++ww)
            delta += __uint_as_float((u32)v[ww]);

        const float xold = xcur[t];
        const float xnew = fmaf(dt, delta + b2r, xold);
        // hist[hidx] (= y_s) and xcur reads of step s all completed before the
        // mid-step barrier; safe to overwrite now.
        hist[hidx][t] = xold;
        xcur[t]       = xnew;
        if (writer) orow[s + 1] = xnew;
        hidx = (hidx + 1 == NTAU) ? 0 : hidx + 1;
        __syncthreads();                       // new state visible to all
    }
}

extern "C" void kernel_launch(void* const* d_in, const int* in_sizes, int n_in,
                              void* d_out, int out_size, void* d_ws, size_t ws_size,
                              hipStream_t stream)
{
    const float* x0  = (const float*)d_in[0];
    const float* W1  = (const float*)d_in[1];
    const float* b1  = (const float*)d_in[2];
    const float* W2  = (const float*)d_in[3];
    const float* b2  = (const float*)d_in[4];
    const int*  taup = (const int*)d_in[5];

    const int Dv = in_sizes[0];           // 256
    const int N  = out_size / Dv - 1;     // 10000

    // P: [2][NWG][DD] u64 tagged slots = 128 KiB in d_ws. 0xAA poison (re-
    // applied by the harness before every launch) never matches a valid tag
    // (tags are 1..N), so no initialization is required.
    u64* P = (u64*)d_ws;

    hipLaunchKernelGGL(ndde_persist, dim3(NWG), dim3(TPB), 0, stream,
                       x0, W1, b1, W2, b2, taup,
                       (float*)d_out, P, N);
}

// Round 7
// 35777.545 us; speedup vs baseline: 2.1084x; 2.1084x over previous
//
#include <hip/hip_runtime.h>
#include <math.h>

// Persistent-kernel DDE solver. D=256, H=1024, N_TAU=10; N from out_size.
// 32 WGs x 256 threads; weights register-resident; per-WG LDS ring for the
// delayed state.
//
// R4: epoch-tagged data polling (publish {tag=s+1, partial} as one 8B relaxed
// agent atomic; gather polls tags directly; no counter, no fences).
// R6 fix: R4's fixup loop polled slot-by-slot serially -> each stale slot a
// DEPENDENT ~900cy coherence round trip (rocprof R6: 75-112ms, +1.3GB poll
// fetch). Now each poll iteration re-sweeps ALL 32 slots as independent
// pipelined loads -> one round trip per iteration regardless of how many
// slots are stale; detect latency ~= skew + 1 RT after the last publisher.
// Slot-reuse safety unchanged: owner WG cannot publish tag s+3 into a slot
// until it gathered all s+2 partials, which data-depend on every WG (incl.
// us) having consumed s+1 -> a ready slot's value cannot change while we
// poll it, so re-reading is benign and the ordered sum stays bitwise-
// deterministic. 0xAA ws-poison never matches a tag (1..N): no init needed.

#define NTAU 10
#define DD   256
#define HH   1024
#define NWG  32
#define TPB  256
#define HPW  (HH / NWG)   // 32 h-rows per WG
#define KPT  64           // z elements per thread (layer 1)

typedef unsigned long long u64;
typedef unsigned int       u32;

__global__ __launch_bounds__(TPB, 1)
void ndde_persist(const float* __restrict__ x0,
                  const float* __restrict__ W1,
                  const float* __restrict__ b1,
                  const float* __restrict__ W2,
                  const float* __restrict__ b2,
                  const int*   __restrict__ taup,
                  float* __restrict__ out,   // [DD][N+1] row-major
                  u64*          P,           // [2][NWG][DD] tagged partials (d_ws)
                  int N)
{
    const int w  = blockIdx.x;     // 0..31
    const int t  = threadIdx.x;    // 0..255
    const int r  = t >> 3;         // row-in-WG 0..31
    const int i  = t & 7;          // k-chunk 0..7 (i<4 -> x part, i>=4 -> y part)
    const int row  = w * HPW + r;  // global h row this (r-group) computes
    const int col0 = w * HPW;      // W2 column base for layer 2

    const float dt = 0.1f * (float)(*taup);

    __shared__ __align__(16) float xcur[DD];
    __shared__ __align__(16) float hist[NTAU][DD];  // ring: slot s%10 holds x_{s-10}
    __shared__ __align__(16) float hsh[HPW];

    // ---- prologue: weights -> registers ----
    // Layer-1 chunk: W1[row][i*64 + 4*((j+i)&15) + c]  (j-rotation by i spreads
    // the 8 per-wave LDS broadcast addresses across 8 distinct bank-quads).
    float4 w1r[16];
    {
        const float* wrow = W1 + (size_t)row * (2 * DD);
        #pragma unroll
        for (int j = 0; j < 16; ++j) {
            int jj = (j + i) & 15;
            w1r[j] = *(const float4*)(wrow + i * KPT + 4 * jj);
        }
    }
    // Layer-2 chunk: W2[t][col0 .. col0+32)
    float4 w2r[8];
    #pragma unroll
    for (int c = 0; c < 8; ++c)
        w2r[c] = *(const float4*)(W2 + (size_t)t * HH + col0 + 4 * c);

    const float b1r = b1[row];
    const float b2r = b2[t];
    const float x0r = x0[t];
    const bool  writer = (r == w);            // WG w owns output rows [8w, 8w+8)
    float* orow = out + (size_t)t * (N + 1);  // this thread's output row

    xcur[t] = x0r;
    #pragma unroll
    for (int q = 0; q < NTAU; ++q) hist[q][t] = x0r;
    if (writer) orow[0] = x0r;
    __syncthreads();

    int hidx = 0;  // s % NTAU
    for (int s = 0; s < N; ++s) {
        // ---- layer 1: acc = sum_k W1[row][chunk] * z[chunk] ----
        const float* zbase = (i < 4) ? (xcur + (i & 3) * KPT)
                                     : (hist[hidx] + (i & 3) * KPT);
        float ax = 0.f, ay = 0.f, az = 0.f, aw = 0.f;  // 4 indep FMA chains
        #pragma unroll
        for (int j = 0; j < 16; ++j) {
            int jj = (j + i) & 15;
            float4 zv = *(const float4*)(zbase + 4 * jj);
            float4 wv = w1r[j];
            ax = fmaf(wv.x, zv.x, ax);
            ay = fmaf(wv.y, zv.y, ay);
            az = fmaf(wv.z, zv.z, az);
            aw = fmaf(wv.w, zv.w, aw);
        }
        float acc = (ax + ay) + (az + aw);
        // reduce the 8 k-chunk lanes (contiguous within wave)
        acc += __shfl_xor(acc, 1);
        acc += __shfl_xor(acc, 2);
        acc += __shfl_xor(acc, 4);
        if (i == 0) hsh[r] = tanhf(acc + b1r);
        __syncthreads();                       // hsh ready for layer 2

        // ---- layer 2: partial_d = sum_c W2[d][col0+c] * h[col0+c] ----
        float px = 0.f, py = 0.f, pz = 0.f, pw = 0.f;
        #pragma unroll
        for (int c = 0; c < 8; ++c) {
            float4 hv = *(const float4*)(&hsh[4 * c]);  // same-addr broadcast
            float4 wv = w2r[c];
            px = fmaf(wv.x, hv.x, px);
            py = fmaf(wv.y, hv.y, py);
            pz = fmaf(wv.z, hv.z, pz);
            pw = fmaf(wv.w, hv.w, pw);
        }
        float p = (px + py) + (pz + pw);

        // ---- publish tagged partial: one 8B relaxed agent atomic store ----
        const u32 tag = (u32)(s + 1);
        u64* slot = P + ((size_t)(s & 1) * NWG + w) * DD + t;
        const u64 pk = ((u64)tag << 32) | (u64)__float_as_uint(p);
        __hip_atomic_store(slot, pk, __ATOMIC_RELAXED, __HIP_MEMORY_SCOPE_AGENT);

        // ---- gather: full pipelined re-sweeps until all 32 tags match ----
        u64* gbase = P + (size_t)(s & 1) * NWG * DD + t;
        u64 v[NWG];
        #pragma unroll
        for (int ww = 0; ww < NWG; ++ww)
            v[ww] = __hip_atomic_load(gbase + (size_t)ww * DD,
                                      __ATOMIC_RELAXED, __HIP_MEMORY_SCOPE_AGENT);
        for (;;) {
            bool ok = true;
            #pragma unroll
            for (int ww = 0; ww < NWG; ++ww)
                ok &= ((u32)(v[ww] >> 32) == tag);
            if (__all((int)ok)) break;         // wave-uniform exit
            #pragma unroll
            for (int ww = 0; ww < NWG; ++ww)   // 32 independent loads: 1 RT
                v[ww] = __hip_atomic_load(gbase + (size_t)ww * DD,
                                          __ATOMIC_RELAXED, __HIP_MEMORY_SCOPE_AGENT);
        }
        float delta = 0.f;
        #pragma unroll
        for (int ww = 0; ww < NWG; ++ww)
            delta += __uint_as_float((u32)v[ww]);

        const float xold = xcur[t];
        const float xnew = fmaf(dt, delta + b2r, xold);
        // hist[hidx] (= y_s) and xcur reads of step s all completed before the
        // mid-step barrier; safe to overwrite now.
        hist[hidx][t] = xold;
        xcur[t]       = xnew;
        if (writer) orow[s + 1] = xnew;
        hidx = (hidx + 1 == NTAU) ? 0 : hidx + 1;
        __syncthreads();                       // new state visible to all
    }
}

extern "C" void kernel_launch(void* const* d_in, const int* in_sizes, int n_in,
                              void* d_out, int out_size, void* d_ws, size_t ws_size,
                              hipStream_t stream)
{
    const float* x0  = (const float*)d_in[0];
    const float* W1  = (const float*)d_in[1];
    const float* b1  = (const float*)d_in[2];
    const float* W2  = (const float*)d_in[3];
    const float* b2  = (const float*)d_in[4];
    const int*  taup = (const int*)d_in[5];

    const int Dv = in_sizes[0];           // 256
    const int N  = out_size / Dv - 1;     // 10000

    // P: [2][NWG][DD] u64 tagged slots = 128 KiB in d_ws. 0xAA poison (re-
    // applied by the harness before every launch) never matches a valid tag
    // (tags are 1..N), so no initialization is required.
    u64* P = (u64*)d_ws;

    hipLaunchKernelGGL(ndde_persist, dim3(NWG), dim3(TPB), 0, stream,
                       x0, W1, b1, W2, b2, taup,
                       (float*)d_out, P, N);
}